// Round 16
// baseline (351.183 us; speedup 1.0000x reference)
//
#include <hip/hip_runtime.h>
#include <math.h>

// B=64 graphs, A=32 atoms, N=2048 nodes, E=65536 edges, H=512, LAT=256, L=4, DIS=60, EIN=1093
// Weights in MFMA B-fragment order; activations (nfP,h1P,aggP) in A-fragment-packed bf16.
// Node GEMMs: LDS-free, M=32xN=32 per block (wave (w>>1,w&1) owns a 16x16 tile) for
// L1-shared operand reuse; chunk-4 unrolled pipelines. fd frags precomputed once.

typedef short bf16x8 __attribute__((ext_vector_type(8)));
typedef float f32x4 __attribute__((ext_vector_type(4)));

__device__ __forceinline__ float silu_f(float x) {
    float e = __builtin_amdgcn_exp2f(x * -1.44269504088896f);
    return x * __builtin_amdgcn_rcpf(1.0f + e);
}
__device__ __forceinline__ unsigned short f2bf(float x) {
    unsigned int u = __float_as_uint(x);
    u += 0x7fffu + ((u >> 16) & 1u);
    return (unsigned short)(u >> 16);
}
__device__ __forceinline__ unsigned int cvt_pk_bf16(float lo, float hi) {
    unsigned int r;
    asm("v_cvt_pk_bf16_f32 %0, %1, %2" : "=v"(r) : "v"(lo), "v"(hi));
    return r;
}
__device__ __forceinline__ size_t apack_idx(int ng, int m, int c) {
    return ((size_t)(ng*16 + (c >> 5))*64 + (m + 16*((c >> 3) & 3)))*8 + (c & 7);
}

// ---- workspace layout (float offsets) ----
#define NF_OFF    0
#define UP_OFF    (2048*512)
#define VTD_OFF   (2*2048*512)
#define NFP_OFF   (VTD_OFF + 1048576)
#define H1P_OFF   (NFP_OFF + 524288)
#define AGGP_OFF  (H1P_OFF + 524288)
#define WBF_OFF   (AGGP_OFF + 524288)
#define SZ_INITT (512*768)
#define SZ_UVT   (1024*512)
#define SZ_W1DT  (512*64)
#define SZ_W2T   (512*512)
#define SZ_NW1T  (512*1024)
#define SZ_NW2T  (512*512)
#define SZ_LAYER (SZ_UVT+SZ_W1DT+SZ_W2T+SZ_NW1T+SZ_NW2T)
#define WBF_FLOATS ((SZ_INITT + 4*SZ_LAYER + 1)/2)
#define FDP_OFF   (WBF_OFF + WBF_FLOATS)

// ---- weight transpose+convert+fragment-pack ----
__global__ __launch_bounds__(256) void k_prep(
    const float* __restrict__ Wl, const float* __restrict__ eW1,
    const float* __restrict__ eW2, const float* __restrict__ nW1,
    const float* __restrict__ nW2, unsigned short* __restrict__ wbf)
{
    __shared__ float tile[32][33];
    int bid = blockIdx.x;
    const float* src; int K; unsigned short* dst; int t;
    if (bid < 384) { src = Wl; K = 768; dst = wbf; t = bid; }
    else {
        int b = bid - 384; int l = b / 1568; int j = b - l * 1568;
        const float* e1 = eW1 + (size_t)l * 1093 * 512;
        unsigned short* base = wbf + SZ_INITT + (size_t)l * SZ_LAYER;
        if (j < 256)      { src = e1;                       K = 512;  dst = base;                                   t = j; }
        else if (j < 512) { src = e1 + 512*512;             K = 512;  dst = base + 512*512;                         t = j-256; }
        else if (j < 544) { src = e1 + 1033*512;            K = 60;   dst = base + SZ_UVT;                          t = j-512; }
        else if (j < 800) { src = eW2 + (size_t)l*512*512;  K = 512;  dst = base + SZ_UVT+SZ_W1DT;                  t = j-544; }
        else if (j <1312) { src = nW1 + (size_t)l*1024*512; K = 1024; dst = base + SZ_UVT+SZ_W1DT+SZ_W2T;           t = j-800; }
        else              { src = nW2 + (size_t)l*512*512;  K = 512;  dst = base + SZ_UVT+SZ_W1DT+SZ_W2T+SZ_NW1T;   t = j-1312; }
    }
    int tr = t >> 4, tc = t & 15;
    int k0 = tr * 32, nn0 = tc * 32;
    {
        int r8 = threadIdx.x >> 5, cc = threadIdx.x & 31;
        #pragma unroll
        for (int rr = 0; rr < 4; ++rr) {
            int row = rr*8 + r8;
            int k = k0 + row;
            tile[row][cc] = (k < K) ? src[(size_t)k*512 + nn0 + cc] : 0.f;
        }
    }
    __syncthreads();
    int nt_loc = threadIdx.x >> 7;
    int l = (threadIdx.x >> 1) & 63;
    int jh = threadIdx.x & 1;
    int lj = l & 15, lh = l >> 4;
    float v0 = tile[lh*8 + jh*4 + 0][nt_loc*16 + lj];
    float v1 = tile[lh*8 + jh*4 + 1][nt_loc*16 + lj];
    float v2 = tile[lh*8 + jh*4 + 2][nt_loc*16 + lj];
    float v3 = tile[lh*8 + jh*4 + 3][nt_loc*16 + lj];
    uint2 pk = { cvt_pk_bf16(v0, v1), cvt_pk_bf16(v2, v3) };
    *(uint2*)&dst[((size_t)(tr*32 + tc*2 + nt_loc)*64 + l)*8 + jh*4] = pk;
}

// fd sinusoid B-fragments
__global__ __launch_bounds__(64) void k_fd(const float* __restrict__ frac,
                                           unsigned short* __restrict__ fdP)
{
    int bid = blockIdx.x;
    int n0 = bid * 2, g = n0 >> 5;
    int l = threadIdx.x, lj = l & 15, lh = l >> 4;
    float di[2][2][3];
    #pragma unroll
    for (int h = 0; h < 2; ++h)
        #pragma unroll
        for (int dd = 0; dd < 2; ++dd) {
            int dstn = g*32 + dd*16 + lj;
            #pragma unroll
            for (int comp = 0; comp < 3; ++comp) {
                float d = frac[dstn*3 + comp] - frac[(n0+h)*3 + comp];
                d -= floorf(d);
                di[h][dd][comp] = d;
            }
        }
    #pragma unroll
    for (int kt = 0; kt < 2; ++kt)
        #pragma unroll
        for (int mt = 0; mt < 4; ++mt) {
            int h = mt >> 1, dd = mt & 1;
            unsigned int w[4];
            #pragma unroll
            for (int p = 0; p < 4; ++p) {
                float vv[2];
                #pragma unroll
                for (int e = 0; e < 2; ++e) {
                    int k = kt*32 + lh*8 + p*2 + e;
                    float val = 0.f;
                    if (k < 60) {
                        int isCos = k >= 30;
                        int dq = k - (isCos ? 30 : 0);
                        int comp = dq >= 20 ? 2 : (dq >= 10 ? 1 : 0);
                        int f = dq - comp*10;
                        float u = di[h][dd][comp] * (float)f;
                        u -= floorf(u);
                        val = isCos ? __builtin_amdgcn_cosf(u) : __builtin_amdgcn_sinf(u);
                    }
                    vv[e] = val;
                }
                w[p] = cvt_pk_bf16(vv[0], vv[1]);
            }
            uint4 pk = { w[0], w[1], w[2], w[3] };
            *(uint4*)&fdP[(((size_t)bid*8 + kt*4 + mt)*64 + l)*8] = pk;
        }
}

// nf0 = concat(emb,t)@Wl + bl : writes nf (f32) and nfP (A-packed bf16)
__global__ __launch_bounds__(256) void k_init(
    const float* __restrict__ tvec, const float* __restrict__ emb,
    const unsigned short* __restrict__ WT, const float* __restrict__ bl,
    const int* __restrict__ atom_types, float* __restrict__ nf,
    unsigned short* __restrict__ nfP)
{
    __shared__ __align__(16) unsigned short cat_s[16*768];
    int ng = blockIdx.x >> 1, half = blockIdx.x & 1;
    int n0 = ng * 16, tid = threadIdx.x;
    for (int idx = tid; idx < 16*192; idx += 256) {
        int m = idx / 192, q = idx - m * 192;
        int k4 = q * 4, n = n0 + m;
        float4 v;
        if (k4 < 512) v = *(const float4*)&emb[(size_t)(atom_types[n]-1)*512 + k4];
        else          v = *(const float4*)&tvec[(size_t)(n>>5)*256 + (k4-512)];
        uint2 pk = { cvt_pk_bf16(v.x, v.y), cvt_pk_bf16(v.z, v.w) };
        *(uint2*)&cat_s[m*768 + (k4 ^ ((m&7)<<3))] = pk;
    }
    __syncthreads();
    int w = tid >> 6, l = tid & 63, lj = l & 15, lh = l >> 4;
    f32x4 acc[4];
    #pragma unroll
    for (int nt = 0; nt < 4; ++nt) acc[nt] = (f32x4){0.f,0.f,0.f,0.f};
    for (int kt = 0; kt < 24; ++kt) {
        int k = kt*32 + lh*8;
        bf16x8 a = *(const bf16x8*)&cat_s[lj*768 + (k ^ ((lj&7)<<3))];
        #pragma unroll
        for (int nt = 0; nt < 4; ++nt) {
            bf16x8 b = *(const bf16x8*)&WT[(((size_t)kt*32 + half*16 + w*4 + nt)*64 + l)*8];
            acc[nt] = __builtin_amdgcn_mfma_f32_16x16x32_bf16(a, b, acc[nt], 0, 0, 0);
        }
    }
    #pragma unroll
    for (int nt = 0; nt < 4; ++nt) {
        int c = half*256 + w*64 + nt*16 + lj;
        float bv = bl[c];
        #pragma unroll
        for (int r = 0; r < 4; ++r) {
            int m = lh*4 + r;
            float v = acc[nt][r] + bv;
            nf[(size_t)(n0 + m)*512 + c] = v;
            nfP[apack_idx(ng, m, c)] = f2bf(v);
        }
    }
}

// LDS-free uv: 1024 blocks (ng 128, half 2, chq 4), nt=2, chunk-2 pipeline.
__global__ __launch_bounds__(256) void k_uv(
    const unsigned short* __restrict__ nfP, const unsigned short* __restrict__ WT,
    const float* __restrict__ lat, const float* __restrict__ W1c,
    const float* __restrict__ b1, float* __restrict__ Up,
    float* __restrict__ VTD)
{
    int ng = blockIdx.x >> 3, half = (blockIdx.x >> 2) & 1, chq = blockIdx.x & 3;
    int n0 = ng * 16, g = n0 >> 5, tid = threadIdx.x;
    int w = tid >> 6, l = tid & 63, lj = l & 15, lh = l >> 4;
    const unsigned short* Wh = WT + (size_t)half*512*512;
    f32x4 acc[2];
    acc[0] = (f32x4){0.f,0.f,0.f,0.f};
    acc[1] = (f32x4){0.f,0.f,0.f,0.f};
    bf16x8 aB[2][2], bB[2][2][2];
    #pragma unroll
    for (int j = 0; j < 2; ++j) {
        aB[0][j] = *(const bf16x8*)&nfP[((size_t)(ng*16 + j)*64 + l)*8];
        #pragma unroll
        for (int nt = 0; nt < 2; ++nt)
            bB[0][j][nt] = *(const bf16x8*)&Wh[(((size_t)j*32 + chq*8 + w*2 + nt)*64 + l)*8];
    }
    #pragma unroll
    for (int c = 0; c < 8; ++c) {
        const int cur = c & 1, nxt = cur ^ 1;
        if (c < 7) {
            #pragma unroll
            for (int j = 0; j < 2; ++j) {
                int kt = (c+1)*2 + j;
                aB[nxt][j] = *(const bf16x8*)&nfP[((size_t)(ng*16 + kt)*64 + l)*8];
                #pragma unroll
                for (int nt = 0; nt < 2; ++nt)
                    bB[nxt][j][nt] = *(const bf16x8*)&Wh[(((size_t)kt*32 + chq*8 + w*2 + nt)*64 + l)*8];
            }
        }
        #pragma unroll
        for (int j = 0; j < 2; ++j)
            #pragma unroll
            for (int nt = 0; nt < 2; ++nt)
                acc[nt] = __builtin_amdgcn_mfma_f32_16x16x32_bf16(aB[cur][j], bB[cur][j][nt], acc[nt], 0, 0, 0);
    }
    if (half == 0) {
        float L[9], lip[9];
        #pragma unroll
        for (int i = 0; i < 9; ++i) L[i] = lat[g*9 + i];
        #pragma unroll
        for (int i = 0; i < 3; ++i)
            #pragma unroll
            for (int kk = 0; kk < 3; ++kk)
                lip[i*3+kk] = L[i*3]*L[kk*3] + L[i*3+1]*L[kk*3+1] + L[i*3+2]*L[kk*3+2];
        #pragma unroll
        for (int nt = 0; nt < 2; ++nt) {
            int c = chq*128 + w*32 + nt*16 + lj;
            float p3 = b1[c];
            #pragma unroll
            for (int t9 = 0; t9 < 9; ++t9) p3 += lip[t9] * W1c[t9*512 + c];
            #pragma unroll
            for (int r = 0; r < 4; ++r)
                Up[(size_t)(n0 + lh*4 + r)*512 + c] = acc[nt][r] + p3;
        }
    } else {
        int dd = (n0 & 31) >> 4;
        #pragma unroll
        for (int nt = 0; nt < 2; ++nt) {
            int ct = chq*8 + w*2 + nt;
            #pragma unroll
            for (int rr = 0; rr < 4; ++rr)
                VTD[(size_t)g*16384 + ct*512 + dd*256 + (lh*4+rr)*16 + lj] = acc[nt][rr];
        }
    }
}

// fused edge pipeline: 2 src nodes/block (M=64), 512 threads (8 waves), grid 1024.
__global__ __launch_bounds__(512) void k_edge(
    const float* __restrict__ Up, const float* __restrict__ VTD,
    const unsigned short* __restrict__ fdP,
    const unsigned short* __restrict__ W1dT,
    const unsigned short* __restrict__ W2T, const float* __restrict__ b2,
    unsigned short* __restrict__ aggP)
{
    __shared__ __align__(16) unsigned short ef1_s[64*512];
    int n0 = blockIdx.x * 2, g = n0 >> 5, tid = threadIdx.x;
    int wid = tid >> 6, l = tid & 63, lj = l & 15, lh = l >> 4;

    // ---------------- stage 1 ----------------
    {
        bf16x8 fdf[2][4];
        #pragma unroll
        for (int kt = 0; kt < 2; ++kt)
            #pragma unroll
            for (int mt = 0; mt < 4; ++mt)
                fdf[kt][mt] = *(const bf16x8*)&fdP[(((size_t)blockIdx.x*8 + kt*4 + mt)*64 + l)*8];

        #pragma unroll
        for (int q = 0; q < 4; ++q) {
            int ct = wid*4 + q;
            f32x4 a1[4];
            #pragma unroll
            for (int mt = 0; mt < 4; ++mt)
                a1[mt] = *(const f32x4*)&VTD[(size_t)g*16384 + ct*512 + (mt&1)*256 + lj*16 + lh*4];
            #pragma unroll
            for (int kt = 0; kt < 2; ++kt) {
                bf16x8 wf = *(const bf16x8*)&W1dT[(((size_t)kt*32 + ct)*64 + l)*8];
                #pragma unroll
                for (int mt = 0; mt < 4; ++mt)
                    a1[mt] = __builtin_amdgcn_mfma_f32_16x16x32_bf16(wf, fdf[kt][mt], a1[mt], 0, 0, 0);
            }
            int c0 = wid*64 + q*16 + lh*4;
            float4 bs0 = *(const float4*)&Up[(size_t)n0*512 + c0];
            float4 bs1 = *(const float4*)&Up[(size_t)(n0+1)*512 + c0];
            #pragma unroll
            for (int mt = 0; mt < 4; ++mt) {
                float4 bb = (mt >> 1) ? bs1 : bs0;
                int m = mt*16 + lj;
                float x0 = silu_f(a1[mt][0] + bb.x);
                float x1 = silu_f(a1[mt][1] + bb.y);
                float x2 = silu_f(a1[mt][2] + bb.z);
                float x3 = silu_f(a1[mt][3] + bb.w);
                uint2 pk = { cvt_pk_bf16(x0, x1), cvt_pk_bf16(x2, x3) };
                *(uint2*)&ef1_s[m*512 + (c0 ^ ((m&7)<<3))] = pk;
            }
        }
    }
    __syncthreads();

    // ---------------- stage 2 (barrier-free, B software-pipelined) ----------------
    f32x4 acc2[4][4];
    #pragma unroll
    for (int mt = 0; mt < 4; ++mt)
        #pragma unroll
        for (int nt = 0; nt < 4; ++nt) acc2[mt][nt] = (f32x4){0.f,0.f,0.f,0.f};

    bf16x8 bcur[4], bnxt[4];
    #pragma unroll
    for (int nt = 0; nt < 4; ++nt)
        bcur[nt] = *(const bf16x8*)&W2T[(((size_t)0*32 + wid*4 + nt)*64 + l)*8];

    for (int kt = 0; kt < 16; ++kt) {
        int k = kt*32 + lh*8;
        bf16x8 af[4];
        #pragma unroll
        for (int mt = 0; mt < 4; ++mt) {
            int m = mt*16 + lj;
            af[mt] = *(const bf16x8*)&ef1_s[m*512 + (k ^ ((m&7)<<3))];
        }
        if (kt < 15) {
            #pragma unroll
            for (int nt = 0; nt < 4; ++nt)
                bnxt[nt] = *(const bf16x8*)&W2T[(((size_t)(kt+1)*32 + wid*4 + nt)*64 + l)*8];
        }
        __builtin_amdgcn_s_setprio(1);
        #pragma unroll
        for (int nt = 0; nt < 4; ++nt) {
            #pragma unroll
            for (int mt = 0; mt < 4; ++mt)
                acc2[mt][nt] = __builtin_amdgcn_mfma_f32_16x16x32_bf16(af[mt], bcur[nt], acc2[mt][nt], 0, 0, 0);
        }
        __builtin_amdgcn_s_setprio(0);
        #pragma unroll
        for (int nt = 0; nt < 4; ++nt) bcur[nt] = bnxt[nt];
    }

    // epilogue: silu + per-node column mean -> aggP (A-packed bf16)
    int ngg = n0 >> 4, m0 = n0 & 15;
    #pragma unroll
    for (int nt = 0; nt < 4; ++nt) {
        int cc = wid*64 + nt*16 + lj;
        float bv = b2[cc];
        float s0 = 0.f, s1 = 0.f;
        #pragma unroll
        for (int mt = 0; mt < 4; ++mt)
            #pragma unroll
            for (int r = 0; r < 4; ++r) {
                float x = silu_f(acc2[mt][nt][r] + bv);
                if (mt < 2) s0 += x; else s1 += x;
            }
        s0 += __shfl_xor(s0, 16); s0 += __shfl_xor(s0, 32);
        s1 += __shfl_xor(s1, 16); s1 += __shfl_xor(s1, 32);
        if (lh == 0) {
            aggP[apack_idx(ngg, m0,     cc)] = f2bf(s0 * (1.0f/32.0f));
            aggP[apack_idx(ngg, m0 + 1, cc)] = f2bf(s1 * (1.0f/32.0f));
        }
    }
}

// LDS-free node GEMM1: 1024 blocks = 64 row-pairs x 16 col-groups; wave (mi,ni)=(w>>1,w&1)
// owns 16x16 tile. chunk-4 pipeline. h1P = silu([nfP,aggP]@nW1 + b1), A-packed.
__global__ __launch_bounds__(256) void k_node1(
    const unsigned short* __restrict__ nfP, const unsigned short* __restrict__ aggP,
    const unsigned short* __restrict__ W1T, const float* __restrict__ b1,
    unsigned short* __restrict__ h1P)
{
    int ng2 = blockIdx.x >> 4, cg = blockIdx.x & 15, tid = threadIdx.x;
    int w = tid >> 6, l = tid & 63, lj = l & 15, lh = l >> 4;
    int mi = w >> 1, ni = w & 1;
    int ngA = ng2*2 + mi, ct = cg*2 + ni;
    f32x4 acc = (f32x4){0.f,0.f,0.f,0.f};
    bf16x8 aB[2][4], bB[2][4];
    #pragma unroll
    for (int j = 0; j < 4; ++j) {
        aB[0][j] = *(const bf16x8*)&nfP[((size_t)(ngA*16 + j)*64 + l)*8];
        bB[0][j] = *(const bf16x8*)&W1T[(((size_t)j*32 + ct)*64 + l)*8];
    }
    #pragma unroll
    for (int c = 0; c < 8; ++c) {
        const int cur = c & 1, nxt = cur ^ 1;
        if (c < 7) {
            #pragma unroll
            for (int j = 0; j < 4; ++j) {
                int kt = (c+1)*4 + j;
                aB[nxt][j] = (kt < 16)
                    ? *(const bf16x8*)&nfP[((size_t)(ngA*16 + kt)*64 + l)*8]
                    : *(const bf16x8*)&aggP[((size_t)(ngA*16 + kt - 16)*64 + l)*8];
                bB[nxt][j] = *(const bf16x8*)&W1T[(((size_t)kt*32 + ct)*64 + l)*8];
            }
        }
        #pragma unroll
        for (int j = 0; j < 4; ++j)
            acc = __builtin_amdgcn_mfma_f32_16x16x32_bf16(aB[cur][j], bB[cur][j], acc, 0, 0, 0);
    }
    int c = ct*16 + lj;
    float bv = b1[c];
    #pragma unroll
    for (int r = 0; r < 4; ++r) {
        int m = lh*4 + r;
        h1P[apack_idx(ngA, m, c)] = f2bf(silu_f(acc[r] + bv));
    }
}

// LDS-free node GEMM2: same M=32xN=32 decomposition. nf += silu(h1P@nW2 + b2); writes nfP.
__global__ __launch_bounds__(256) void k_node2(
    float* __restrict__ nf, const unsigned short* __restrict__ h1P,
    const unsigned short* __restrict__ W2T, const float* __restrict__ b2,
    unsigned short* __restrict__ nfP)
{
    int ng2 = blockIdx.x >> 4, cg = blockIdx.x & 15, tid = threadIdx.x;
    int w = tid >> 6, l = tid & 63, lj = l & 15, lh = l >> 4;
    int mi = w >> 1, ni = w & 1;
    int ngA = ng2*2 + mi, ct = cg*2 + ni;
    f32x4 acc = (f32x4){0.f,0.f,0.f,0.f};
    bf16x8 aB[2][4], bB[2][4];
    #pragma unroll
    for (int j = 0; j < 4; ++j) {
        aB[0][j] = *(const bf16x8*)&h1P[((size_t)(ngA*16 + j)*64 + l)*8];
        bB[0][j] = *(const bf16x8*)&W2T[(((size_t)j*32 + ct)*64 + l)*8];
    }
    #pragma unroll
    for (int c = 0; c < 4; ++c) {
        const int cur = c & 1, nxt = cur ^ 1;
        if (c < 3) {
            #pragma unroll
            for (int j = 0; j < 4; ++j) {
                int kt = (c+1)*4 + j;
                aB[nxt][j] = *(const bf16x8*)&h1P[((size_t)(ngA*16 + kt)*64 + l)*8];
                bB[nxt][j] = *(const bf16x8*)&W2T[(((size_t)kt*32 + ct)*64 + l)*8];
            }
        }
        #pragma unroll
        for (int j = 0; j < 4; ++j)
            acc = __builtin_amdgcn_mfma_f32_16x16x32_bf16(aB[cur][j], bB[cur][j], acc, 0, 0, 0);
    }
    int c = ct*16 + lj;
    float bv = b2[c];
    #pragma unroll
    for (int r = 0; r < 4; ++r) {
        int m = lh*4 + r;
        size_t o = (size_t)(ngA*16 + m)*512 + c;
        float v = nf[o] + silu_f(acc[r] + bv);
        nf[o] = v;
        nfP[apack_idx(ngA, m, c)] = f2bf(v);
    }
}

// fused outputs: block b handles graph b — coord for its 32 nodes + lattice head.
__global__ __launch_bounds__(256) void k_out(const float* __restrict__ nf,
                                             const float* __restrict__ cW,
                                             const float* __restrict__ lW,
                                             const float* __restrict__ lat,
                                             float* __restrict__ out) {
    __shared__ float gf[512];
    __shared__ float lo9[9];
    int b = blockIdx.x, tid = threadIdx.x;
    // coord: thread (node nl, k-slice s)
    {
        int nl = tid >> 3, s = tid & 7;
        int n = b*32 + nl;
        const float* row = nf + (size_t)n*512 + s*64;
        float p0 = 0.f, p1 = 0.f, p2 = 0.f;
        #pragma unroll
        for (int k4 = 0; k4 < 64; k4 += 4) {
            float4 v = *(const float4*)&row[k4];
            int kg = s*64 + k4;
            p0 += v.x*cW[(kg+0)*3+0] + v.y*cW[(kg+1)*3+0] + v.z*cW[(kg+2)*3+0] + v.w*cW[(kg+3)*3+0];
            p1 += v.x*cW[(kg+0)*3+1] + v.y*cW[(kg+1)*3+1] + v.z*cW[(kg+2)*3+1] + v.w*cW[(kg+3)*3+1];
            p2 += v.x*cW[(kg+0)*3+2] + v.y*cW[(kg+1)*3+2] + v.z*cW[(kg+2)*3+2] + v.w*cW[(kg+3)*3+2];
        }
        p0 += __shfl_xor(p0, 1); p0 += __shfl_xor(p0, 2); p0 += __shfl_xor(p0, 4);
        p1 += __shfl_xor(p1, 1); p1 += __shfl_xor(p1, 2); p1 += __shfl_xor(p1, 4);
        p2 += __shfl_xor(p2, 1); p2 += __shfl_xor(p2, 2); p2 += __shfl_xor(p2, 4);
        if (s == 0) {
            out[576 + n*3 + 0] = p0;
            out[576 + n*3 + 1] = p1;
            out[576 + n*3 + 2] = p2;
        }
    }
    // graph mean + lattice head
    float s0 = 0.f, s1 = 0.f;
    for (int r = 0; r < 32; ++r) {
        s0 += nf[(size_t)(b*32 + r)*512 + tid];
        s1 += nf[(size_t)(b*32 + r)*512 + tid + 256];
    }
    gf[tid]       = s0 * (1.f/32.f);
    gf[tid + 256] = s1 * (1.f/32.f);
    __syncthreads();
    if (tid < 9) {
        float s = 0.f;
        for (int k = 0; k < 512; ++k) s += gf[k] * lW[k*9 + tid];
        lo9[tid] = s;
    }
    __syncthreads();
    if (tid < 9) {
        int i = tid / 3, kk = tid - (tid/3)*3;
        float s = lo9[i*3+0]*lat[b*9 + 0*3 + kk]
                + lo9[i*3+1]*lat[b*9 + 1*3 + kk]
                + lo9[i*3+2]*lat[b*9 + 2*3 + kk];
        out[b*9 + tid] = s;
    }
}

extern "C" void kernel_launch(void* const* d_in, const int* in_sizes, int n_in,
                              void* d_out, int out_size, void* d_ws, size_t ws_size,
                              hipStream_t stream)
{
    const float* t    = (const float*)d_in[0];
    const float* frac = (const float*)d_in[1];
    const float* lat  = (const float*)d_in[2];
    const float* emb  = (const float*)d_in[3];
    const float* Wl   = (const float*)d_in[4];
    const float* bl   = (const float*)d_in[5];
    const float* eW1  = (const float*)d_in[6];
    const float* eb1  = (const float*)d_in[7];
    const float* eW2  = (const float*)d_in[8];
    const float* eb2  = (const float*)d_in[9];
    const float* nW1  = (const float*)d_in[10];
    const float* nb1  = (const float*)d_in[11];
    const float* nW2  = (const float*)d_in[12];
    const float* nb2  = (const float*)d_in[13];
    const float* cW   = (const float*)d_in[14];
    const float* lW   = (const float*)d_in[15];
    const int* atom_types = (const int*)d_in[16];

    float* out  = (float*)d_out;
    float* wsf  = (float*)d_ws;
    float* nf   = wsf + NF_OFF;
    float* Up   = wsf + UP_OFF;
    float* VTD  = wsf + VTD_OFF;
    unsigned short* nfP  = (unsigned short*)(wsf + NFP_OFF);
    unsigned short* h1P  = (unsigned short*)(wsf + H1P_OFF);
    unsigned short* aggP = (unsigned short*)(wsf + AGGP_OFF);
    unsigned short* wbf  = (unsigned short*)(wsf + WBF_OFF);
    unsigned short* fdP  = (unsigned short*)(wsf + FDP_OFF);

    k_prep<<<384 + 4*1568, 256, 0, stream>>>(Wl, eW1, eW2, nW1, nW2, wbf);
    k_fd<<<1024, 64, 0, stream>>>(frac, fdP);
    k_init<<<256, 256, 0, stream>>>(t, emb, wbf, bl, atom_types, nf, nfP);
    for (int l = 0; l < 4; ++l) {
        const unsigned short* base = wbf + SZ_INITT + (size_t)l * SZ_LAYER;
        const unsigned short* w1dT = base + SZ_UVT;
        const unsigned short* w2T  = w1dT + SZ_W1DT;
        const unsigned short* nw1T = w2T + SZ_W2T;
        const unsigned short* nw2T = nw1T + SZ_NW1T;
        k_uv<<<1024, 256, 0, stream>>>(nfP, base, lat,
                                       eW1 + (size_t)l*1093*512 + 1024*512,
                                       eb1 + l*512, Up, VTD);
        k_edge<<<1024, 512, 0, stream>>>(Up, VTD, fdP, w1dT, w2T,
                                         eb2 + l*512, aggP);
        k_node1<<<1024, 256, 0, stream>>>(nfP, aggP, nw1T, nb1 + l*512, h1P);
        k_node2<<<1024, 256, 0, stream>>>(nf, h1P, nw2T, nb2 + l*512, nfP);
    }
    k_out<<<64, 256, 0, stream>>>(nf, cW, lW, lat, out);
}